// Round 1
// baseline (379.997 us; speedup 1.0000x reference)
//
#include <hip/hip_runtime.h>
#include <cstdint>
#include <cstddef>

// Round 1: x_dq == x exactly (pow2 scales), so op = bf16 MFMA GEMM
//   y = x @ (w * bf16(scale))^T + bias
// Phase A: convert x -> bf16, dequant w -> bf16 (into d_ws, 96 MB)
// Phase B: m97-structure 128x128 GEMM, global_load_lds(16B), 16x16x32 MFMA.

typedef __attribute__((ext_vector_type(8))) __bf16 bf16x8;
typedef __attribute__((ext_vector_type(4))) float f32x4;

__device__ __forceinline__ unsigned short bf16rn(float f) {
  unsigned u = __builtin_bit_cast(unsigned, f);
  u = (u + 0x7FFFu + ((u >> 16) & 1u)) >> 16;
  return (unsigned short)u;
}

__device__ __forceinline__ float bf16tof(unsigned short h) {
  unsigned u = ((unsigned)h) << 16;
  return __builtin_bit_cast(float, u);
}

__device__ __forceinline__ void gload_lds16(const void* g, void* l) {
  __builtin_amdgcn_global_load_lds(
      (const __attribute__((address_space(1))) unsigned int*)g,
      (__attribute__((address_space(3))) unsigned int*)l, 16, 0, 0);
}

// ---------------- Phase A kernels ----------------

__global__ __launch_bounds__(256) void k_convert_x(
    const float* __restrict__ x, unsigned short* __restrict__ xb, int n8) {
  int t = blockIdx.x * 256 + threadIdx.x;
  if (t >= n8) return;
  const float4* p = (const float4*)x + (size_t)t * 2;
  float4 a = p[0], b = p[1];
  uint4 o;
  o.x = (unsigned)bf16rn(a.x) | ((unsigned)bf16rn(a.y) << 16);
  o.y = (unsigned)bf16rn(a.z) | ((unsigned)bf16rn(a.w) << 16);
  o.z = (unsigned)bf16rn(b.x) | ((unsigned)bf16rn(b.y) << 16);
  o.w = (unsigned)bf16rn(b.z) | ((unsigned)bf16rn(b.w) << 16);
  ((uint4*)xb)[t] = o;
}

__global__ __launch_bounds__(256) void k_dequant_w(
    const float* __restrict__ w, const float* __restrict__ sc,
    unsigned short* __restrict__ wb, int K, int nblk, int blk, int n8) {
  int t = blockIdx.x * 256 + threadIdx.x;
  if (t >= n8) return;
  size_t base = (size_t)t * 8;
  int o_row = (int)(base / (size_t)K);
  int k = (int)(base % (size_t)K);
  float s = bf16tof(bf16rn(sc[(size_t)o_row * nblk + k / blk]));  // bf16(scale) like ref
  const float4* p = (const float4*)w + (size_t)t * 2;
  float4 a = p[0], b = p[1];
  uint4 o;
  o.x = (unsigned)bf16rn(a.x * s) | ((unsigned)bf16rn(a.y * s) << 16);
  o.y = (unsigned)bf16rn(a.z * s) | ((unsigned)bf16rn(a.w * s) << 16);
  o.z = (unsigned)bf16rn(b.x * s) | ((unsigned)bf16rn(b.y * s) << 16);
  o.w = (unsigned)bf16rn(b.z * s) | ((unsigned)bf16rn(b.w * s) << 16);
  ((uint4*)wb)[t] = o;
}

// ---------------- Phase B: GEMM ----------------
// C[M][N] = A[M][K] * B[N][K]^T + bias, all bf16 in / f32 out.
// 128x128 tile, BK=64, 256 threads (4 waves, 2x2), 16x16x32 bf16 MFMA.

#define BM 128
#define BN 128
#define BK 64

__global__ __launch_bounds__(256, 2) void k_gemm(
    const unsigned short* __restrict__ A, const unsigned short* __restrict__ B,
    const float* __restrict__ bias, float* __restrict__ C,
    int M, int N, int K) {
  __shared__ __align__(16) unsigned short lsA[BM * BK];
  __shared__ __align__(16) unsigned short lsB[BN * BK];

  const int nbn = N / BN;
  const int nwg = gridDim.x;
  int bid = blockIdx.x;
  int wg = bid;
  if ((nwg & 7) == 0) {                 // XCD-aware swizzle (bijective: nwg%8==0)
    wg = (bid & 7) * (nwg >> 3) + (bid >> 3);
  }
  const int m0 = (wg / nbn) * BM;
  const int n0 = (wg % nbn) * BN;

  const int tid = threadIdx.x;
  const int wid = tid >> 6;
  const int lane = tid & 63;
  const int wr = wid >> 1, wc = wid & 1;

  // staging: chunk c = r*4+wid covers rows c*8..c*8+8 of the tile;
  // lane l -> row c*8 + l/8, cols (l%8)*8..+8  == LDS bytes c*1024 + l*16
  const unsigned short* gA =
      A + (size_t)(m0 + wid * 8 + (lane >> 3)) * K + ((lane & 7) << 3);
  const unsigned short* gB =
      B + (size_t)(n0 + wid * 8 + (lane >> 3)) * K + ((lane & 7) << 3);
  char* lAb = (char*)lsA + wid * 1024;
  char* lBb = (char*)lsB + wid * 1024;

  f32x4 acc[4][4] = {};

  const int rowA = wr * 64 + (lane & 15);
  const int rowB = wc * 64 + (lane & 15);
  const int ko0 = (lane >> 4) * 8;

  for (int k = 0; k < K; k += BK) {
    __syncthreads();  // previous tile's compute done; LDS reusable
#pragma unroll
    for (int r = 0; r < 4; ++r) {
      gload_lds16(gA + (size_t)(r * 32) * K + k, lAb + r * 4096);
      gload_lds16(gB + (size_t)(r * 32) * K + k, lBb + r * 4096);
    }
    __syncthreads();  // implies vmcnt(0): staged data visible
#pragma unroll
    for (int kk = 0; kk < 2; ++kk) {
      const int ko = kk * 32 + ko0;
      bf16x8 af[4], bfr[4];
#pragma unroll
      for (int i = 0; i < 4; ++i)
        af[i] = *(const bf16x8*)(lsA + (rowA + i * 16) * BK + ko);
#pragma unroll
      for (int j = 0; j < 4; ++j)
        bfr[j] = *(const bf16x8*)(lsB + (rowB + j * 16) * BK + ko);
#pragma unroll
      for (int i = 0; i < 4; ++i)
#pragma unroll
        for (int j = 0; j < 4; ++j)
          acc[i][j] = __builtin_amdgcn_mfma_f32_16x16x32_bf16(
              af[i], bfr[j], acc[i][j], 0, 0, 0);
    }
  }

  // epilogue: C/D layout col = lane&15, row = (lane>>4)*4 + reg  [m89/m91]
  const int col0 = n0 + wc * 64 + (lane & 15);
  const int row00 = m0 + wr * 64 + ((lane >> 4) << 2);
#pragma unroll
  for (int j = 0; j < 4; ++j) {
    float bj = bias[col0 + j * 16];
#pragma unroll
    for (int i = 0; i < 4; ++i) {
#pragma unroll
      for (int r = 0; r < 4; ++r) {
        C[(size_t)(row00 + i * 16 + r) * N + (col0 + j * 16)] = acc[i][j][r] + bj;
      }
    }
  }
}

// ---------------- fallback (exact f32, only if ws too small) ----------------

__global__ __launch_bounds__(256) void k_fallback(
    const float* __restrict__ x, const float* __restrict__ w,
    const float* __restrict__ sc, const float* __restrict__ bias,
    float* __restrict__ out, int T, int O, int K, int nblk, int blk) {
  long long idx = (long long)blockIdx.x * 256 + threadIdx.x;
  if (idx >= (long long)T * O) return;
  int row = (int)(idx / O), col = (int)(idx % O);
  const float* xr = x + (size_t)row * K;
  const float* wr = w + (size_t)col * K;
  const float* sr = sc + (size_t)col * nblk;
  float acc = 0.f;
  for (int b = 0; b < nblk; ++b) {
    float s = bf16tof(bf16rn(sr[b]));
    float part = 0.f;
    for (int k = 0; k < blk; k += 4) {
      float4 xa = *(const float4*)(xr + b * blk + k);
      float4 wa = *(const float4*)(wr + b * blk + k);
      part += xa.x * wa.x + xa.y * wa.y + xa.z * wa.z + xa.w * wa.w;
    }
    acc += part * s;
  }
  out[idx] = acc + bias[col];
}

extern "C" void kernel_launch(void* const* d_in, const int* in_sizes, int n_in,
                              void* d_out, int out_size, void* d_ws, size_t ws_size,
                              hipStream_t stream) {
  const float* x = (const float*)d_in[0];
  const float* w = (const float*)d_in[1];
  const float* sc = (const float*)d_in[2];
  const float* bias = (const float*)d_in[3];
  float* out = (float*)d_out;

  const int x_n = in_sizes[0];
  const int w_n = in_sizes[1];
  const int s_n = in_sizes[2];
  const int O = in_sizes[3];
  const int K = w_n / O;
  const int T = x_n / K;
  const int nblk = s_n / O;
  const int blk = K / nblk;

  const size_t need = (size_t)x_n * 2 + (size_t)w_n * 2;
  const bool tiled_ok = ws_size >= need && (K % BK) == 0 && (T % BM) == 0 &&
                        (O % BN) == 0 && (blk % 8) == 0;

  if (tiled_ok) {
    unsigned short* xb = (unsigned short*)d_ws;
    unsigned short* wb = xb + (size_t)x_n;
    int n8x = x_n / 8, n8w = w_n / 8;
    k_convert_x<<<(n8x + 255) / 256, 256, 0, stream>>>(x, xb, n8x);
    k_dequant_w<<<(n8w + 255) / 256, 256, 0, stream>>>(w, sc, wb, K, nblk, blk, n8w);
    dim3 grid((T / BM) * (O / BN));
    k_gemm<<<grid, 256, 0, stream>>>(xb, wb, bias, out, T, O, K);
  } else {
    long long total = (long long)T * O;
    dim3 grid((unsigned)((total + 255) / 256));
    k_fallback<<<grid, 256, 0, stream>>>(x, w, sc, bias, out, T, O, K, nblk, blk);
  }
}

// Round 2
// 293.479 us; speedup vs baseline: 1.2948x; 1.2948x over previous
//
#include <hip/hip_runtime.h>
#include <cstdint>
#include <cstddef>

// Round 2: 256x256 8-phase GEMM (T1 XCD-swizzle + T2 LDS XOR-swizzle +
// T3/T4 8-phase counted-vmcnt + T5 setprio), plain HIP per m201 template.
// y = x_bf16 @ (w*bf16(scale))_bf16^T + bias  (x_dq == x exactly: pow2 scales)

typedef __attribute__((ext_vector_type(8))) __bf16 bf16x8;
typedef __attribute__((ext_vector_type(4))) float f32x4;

__device__ __forceinline__ unsigned short bf16rn(float f) {
  unsigned u = __builtin_bit_cast(unsigned, f);
  u = (u + 0x7FFFu + ((u >> 16) & 1u)) >> 16;
  return (unsigned short)u;
}
__device__ __forceinline__ float bf16tof(unsigned short h) {
  unsigned u = ((unsigned)h) << 16;
  return __builtin_bit_cast(float, u);
}
__device__ __forceinline__ void gload_lds16(const void* g, void* l) {
  __builtin_amdgcn_global_load_lds(
      (const __attribute__((address_space(1))) unsigned int*)g,
      (__attribute__((address_space(3))) unsigned int*)l, 16, 0, 0);
}

// ---------------- Phase A: conversion kernels ----------------

__global__ __launch_bounds__(256) void k_convert_x(
    const float* __restrict__ x, unsigned short* __restrict__ xb, int n8) {
  int t = blockIdx.x * 256 + threadIdx.x;
  if (t >= n8) return;
  const float4* p = (const float4*)x + (size_t)t * 2;
  float4 a = p[0], b = p[1];
  uint4 o;
  o.x = (unsigned)bf16rn(a.x) | ((unsigned)bf16rn(a.y) << 16);
  o.y = (unsigned)bf16rn(a.z) | ((unsigned)bf16rn(a.w) << 16);
  o.z = (unsigned)bf16rn(b.x) | ((unsigned)bf16rn(b.y) << 16);
  o.w = (unsigned)bf16rn(b.z) | ((unsigned)bf16rn(b.w) << 16);
  ((uint4*)xb)[t] = o;
}

__global__ __launch_bounds__(256) void k_dequant_w(
    const float* __restrict__ w, const float* __restrict__ sc,
    unsigned short* __restrict__ wb, int K, int nblk, int blk, int n8) {
  int t = blockIdx.x * 256 + threadIdx.x;
  if (t >= n8) return;
  size_t base = (size_t)t * 8;
  int o_row = (int)(base / (size_t)K);
  int k = (int)(base % (size_t)K);
  float s = bf16tof(bf16rn(sc[(size_t)o_row * nblk + k / blk]));
  const float4* p = (const float4*)w + (size_t)t * 2;
  float4 a = p[0], b = p[1];
  uint4 o;
  o.x = (unsigned)bf16rn(a.x * s) | ((unsigned)bf16rn(a.y * s) << 16);
  o.y = (unsigned)bf16rn(a.z * s) | ((unsigned)bf16rn(a.w * s) << 16);
  o.z = (unsigned)bf16rn(b.x * s) | ((unsigned)bf16rn(b.y * s) << 16);
  o.w = (unsigned)bf16rn(b.z * s) | ((unsigned)bf16rn(b.w * s) << 16);
  ((uint4*)wb)[t] = o;
}

// ---------------- Phase B: 256^2 8-phase GEMM ----------------
// C[M][N] = A[M][K] * B[N][K]^T + bias. 512 thr = 8 waves (2Mx4N).
// LDS 128 KiB: 2 bufs x (A[256][64] + B[256][64]) bf16. XOR swizzle:
// byte ^= (row&7)<<4 per row (inverse-applied on global src, rule 21).

#define BM 256
#define BN 256
#define BK 64

#define BAR() __builtin_amdgcn_s_barrier()
#define WAIT_LGKM0() asm volatile("s_waitcnt lgkmcnt(0)" ::: "memory")
#define WAIT_VM(n) asm volatile("s_waitcnt vmcnt(" #n ")" ::: "memory")
#define SCHEDB() __builtin_amdgcn_sched_barrier(0)
#define PRIO(p) __builtin_amdgcn_s_setprio(p)

// stage one 64-row quarter (8 KB) of A or B for K-tile `tile` into buf
#define STG_A(buf, q, tile)                                               \
  gload_lds16(Ag + (size_t)(q) * 64 * Ks + (size_t)(tile) * BK,           \
              smem + (buf) * 65536 + (q) * 8192 + tid16)
#define STG_B(buf, q, tile)                                               \
  gload_lds16(Bg + (size_t)(q) * 64 * Ks + (size_t)(tile) * BK,           \
              smem + (buf) * 65536 + 32768 + (q) * 8192 + tid16)

// read 4 A row-frags x 2 kk (8 x ds_read_b128), swizzled
#define READ_A(arr, buf, qm)                                              \
  _Pragma("unroll") for (int i_ = 0; i_ < 4; ++i_) {                      \
    arr[i_][0] = *(const bf16x8*)(smem + (buf) * 65536 +                  \
        (wr * 128 + (qm) * 64 + i_ * 16 + lr) * 128 + ko0);               \
    arr[i_][1] = *(const bf16x8*)(smem + (buf) * 65536 +                  \
        (wr * 128 + (qm) * 64 + i_ * 16 + lr) * 128 + ko1);               \
  }
// read 2 B col-frags x 2 kk (4 x ds_read_b128), swizzled
#define READ_B(arr, buf, qn)                                              \
  _Pragma("unroll") for (int j_ = 0; j_ < 2; ++j_) {                      \
    arr[j_][0] = *(const bf16x8*)(smem + (buf) * 65536 + 32768 +          \
        (wc * 64 + (qn) * 32 + j_ * 16 + lr) * 128 + ko0);                \
    arr[j_][1] = *(const bf16x8*)(smem + (buf) * 65536 + 32768 +          \
        (wc * 64 + (qn) * 32 + j_ * 16 + lr) * 128 + ko1);                \
  }
// 16 MFMA: one C quadrant (4x2 frags) x K=64
#define MFMA_Q(qm, qn, aarr, barr)                                        \
  _Pragma("unroll") for (int kk_ = 0; kk_ < 2; ++kk_)                     \
  _Pragma("unroll") for (int i_ = 0; i_ < 4; ++i_)                        \
  _Pragma("unroll") for (int j_ = 0; j_ < 2; ++j_)                        \
    acc[(qm) * 4 + i_][(qn) * 2 + j_] =                                   \
        __builtin_amdgcn_mfma_f32_16x16x32_bf16(                          \
            aarr[i_][kk_], barr[j_][kk_],                                 \
            acc[(qm) * 4 + i_][(qn) * 2 + j_], 0, 0, 0);

__global__ __launch_bounds__(512, 2) void k_gemm256(
    const unsigned short* __restrict__ A, const unsigned short* __restrict__ B,
    const float* __restrict__ bias, float* __restrict__ C,
    int M, int N, int K) {
  extern __shared__ __align__(16) char smem[];

  const int nbn = N / BN;
  const int nwg = gridDim.x;
  int bid = blockIdx.x;
  int wg = bid;
  if ((nwg & 7) == 0) wg = (bid & 7) * (nwg >> 3) + (bid >> 3);  // T1
  const int m0 = (wg / nbn) * BM;
  const int n0 = (wg % nbn) * BN;

  const int tid = threadIdx.x;
  const int lane = tid & 63;
  const int wid = tid >> 6;
  const int wr = wid >> 2;   // 0..1 -> 128 rows
  const int wc = wid & 3;    // 0..3 -> 64 cols
  const int lr = lane & 15;
  // swizzled k-offset bytes: (kk*64 | (lane>>4)*16) ^ ((lane&7)<<4)
  const int ko0 = (((lane >> 4) * 16) ^ ((lane & 7) << 4));
  const int ko1 = ((64 | ((lane >> 4) * 16)) ^ ((lane & 7) << 4));
  const int tid16 = tid * 16;

  // staging source (pre-swizzled granule so linear LDS dest == swizzled layout)
  const int srow = tid >> 3;                       // 0..63 within quarter
  const int sgran = (tid & 7) ^ (srow & 7);        // inverse swizzle on source
  const size_t Ks = (size_t)K;
  const unsigned short* Ag = A + (size_t)(m0 + srow) * Ks + sgran * 8;
  const unsigned short* Bg = B + (size_t)(n0 + srow) * Ks + sgran * 8;

  f32x4 acc[8][4] = {};
  bf16x8 a0[4][2], a1[4][2], b0[2][2], b1[2][2];

  const int NT = K / BK;
  const int NITER = NT / 2;

  // prologue: tile0 fully (8 quarter-stages), tile1 first 6
  STG_A(0, 0, 0); STG_A(0, 2, 0); STG_B(0, 0, 0); STG_B(0, 1, 0);
  STG_A(0, 1, 0); STG_A(0, 3, 0); STG_B(0, 2, 0); STG_B(0, 3, 0);
  STG_A(1, 0, 1); STG_A(1, 2, 1); STG_B(1, 0, 1); STG_B(1, 1, 1);
  STG_A(1, 1, 1); STG_A(1, 3, 1);
  WAIT_VM(6);  // tile0 landed; tile1's 6 still in flight
  BAR();

  for (int it = 0; it < NITER; ++it) {
    const int t = 2 * it;
    const bool s2 = (t + 2) < NT;
    const bool s3 = (t + 3) < NT;
    // ---- P1: Q(0,0) of tile t (buf0); stage B{2,3} of t+1 -> buf1
    SCHEDB();
    READ_A(a0, 0, 0); READ_B(b0, 0, 0);
    STG_B(1, 2, t + 1); STG_B(1, 3, t + 1);
    SCHEDB(); BAR(); WAIT_LGKM0(); SCHEDB();
    PRIO(1); MFMA_Q(0, 0, a0, b0); PRIO(0); SCHEDB(); BAR();
    // ---- P2: Q(0,1); stage A{0,2} of t+2 -> buf0 (read finished P1)
    SCHEDB();
    READ_B(b1, 0, 1);
    if (s2) { STG_A(0, 0, t + 2); STG_A(0, 2, t + 2); }
    SCHEDB(); BAR(); WAIT_LGKM0(); SCHEDB();
    PRIO(1); MFMA_Q(0, 1, a0, b1); PRIO(0); SCHEDB(); BAR();
    // ---- P3: Q(1,0); stage B{0,1} of t+2 (read finished P2)
    SCHEDB();
    READ_A(a1, 0, 1);
    if (s2) { STG_B(0, 0, t + 2); STG_B(0, 1, t + 2); }
    SCHEDB(); BAR(); WAIT_LGKM0(); SCHEDB();
    PRIO(1); MFMA_Q(1, 0, a1, b0); PRIO(0); SCHEDB(); BAR();
    // ---- P4: Q(1,1); stage A{1,3} of t+2 (read finished P3); vmcnt -> t+1 landed
    SCHEDB();
    if (s2) { STG_A(0, 1, t + 2); STG_A(0, 3, t + 2); WAIT_VM(6); }
    else    { WAIT_VM(0); }
    BAR(); SCHEDB();
    PRIO(1); MFMA_Q(1, 1, a1, b1); PRIO(0); SCHEDB(); BAR();
    // ---- P5: Q(0,0) of tile t+1 (buf1); stage B{2,3} of t+2 (read finished P2)
    SCHEDB();
    READ_A(a0, 1, 0); READ_B(b0, 1, 0);
    if (s2) { STG_B(0, 2, t + 2); STG_B(0, 3, t + 2); }
    SCHEDB(); BAR(); WAIT_LGKM0(); SCHEDB();
    PRIO(1); MFMA_Q(0, 0, a0, b0); PRIO(0); SCHEDB(); BAR();
    // ---- P6: Q(0,1); stage A{0,2} of t+3 -> buf1 (read finished P5)
    SCHEDB();
    READ_B(b1, 1, 1);
    if (s3) { STG_A(1, 0, t + 3); STG_A(1, 2, t + 3); }
    SCHEDB(); BAR(); WAIT_LGKM0(); SCHEDB();
    PRIO(1); MFMA_Q(0, 1, a0, b1); PRIO(0); SCHEDB(); BAR();
    // ---- P7: Q(1,0); stage B{0,1} of t+3 (read finished P6)
    SCHEDB();
    READ_A(a1, 1, 1);
    if (s3) { STG_B(1, 0, t + 3); STG_B(1, 1, t + 3); }
    SCHEDB(); BAR(); WAIT_LGKM0(); SCHEDB();
    PRIO(1); MFMA_Q(1, 0, a1, b0); PRIO(0); SCHEDB(); BAR();
    // ---- P8: Q(1,1); stage A{1,3} of t+3 (read finished P7); vmcnt -> t+2 landed
    SCHEDB();
    if (s3)      { STG_A(1, 1, t + 3); STG_A(1, 3, t + 3); WAIT_VM(6); }
    else if (s2) { WAIT_VM(0); }
    BAR(); SCHEDB();
    PRIO(1); MFMA_Q(1, 1, a1, b1); PRIO(0); SCHEDB(); BAR();
  }

  // epilogue: frag (i,j) at (i*16, j*16); col=lane&15, row=(lane>>4)*4+r
  const int col0 = n0 + wc * 64 + (lane & 15);
  const int row0 = m0 + wr * 128 + ((lane >> 4) << 2);
#pragma unroll
  for (int j = 0; j < 4; ++j) {
    float bj = bias[col0 + j * 16];
#pragma unroll
    for (int i = 0; i < 8; ++i) {
#pragma unroll
      for (int r = 0; r < 4; ++r) {
        C[(size_t)(row0 + i * 16 + r) * N + (col0 + j * 16)] = acc[i][j][r] + bj;
      }
    }
  }
}

// ---------------- fallback (exact f32) ----------------

__global__ __launch_bounds__(256) void k_fallback(
    const float* __restrict__ x, const float* __restrict__ w,
    const float* __restrict__ sc, const float* __restrict__ bias,
    float* __restrict__ out, int T, int O, int K, int nblk, int blk) {
  long long idx = (long long)blockIdx.x * 256 + threadIdx.x;
  if (idx >= (long long)T * O) return;
  int row = (int)(idx / O), col = (int)(idx % O);
  const float* xr = x + (size_t)row * K;
  const float* wr = w + (size_t)col * K;
  const float* sr = sc + (size_t)col * nblk;
  float acc = 0.f;
  for (int b = 0; b < nblk; ++b) {
    float s = bf16tof(bf16rn(sr[b]));
    float part = 0.f;
    for (int k = 0; k < blk; k += 4) {
      float4 xa = *(const float4*)(xr + b * blk + k);
      float4 wa = *(const float4*)(wr + b * blk + k);
      part += xa.x * wa.x + xa.y * wa.y + xa.z * wa.z + xa.w * wa.w;
    }
    acc += part * s;
  }
  out[idx] = acc + bias[col];
}

extern "C" void kernel_launch(void* const* d_in, const int* in_sizes, int n_in,
                              void* d_out, int out_size, void* d_ws, size_t ws_size,
                              hipStream_t stream) {
  const float* x = (const float*)d_in[0];
  const float* w = (const float*)d_in[1];
  const float* sc = (const float*)d_in[2];
  const float* bias = (const float*)d_in[3];
  float* out = (float*)d_out;

  const int x_n = in_sizes[0];
  const int w_n = in_sizes[1];
  const int s_n = in_sizes[2];
  const int O = in_sizes[3];
  const int K = w_n / O;
  const int T = x_n / K;
  const int nblk = s_n / O;
  const int blk = K / nblk;

  const size_t need = (size_t)x_n * 2 + (size_t)w_n * 2;
  const bool tiled_ok = ws_size >= need && (K % (2 * BK)) == 0 &&
                        (T % BM) == 0 && (O % BN) == 0 && (blk % 8) == 0 &&
                        K >= 2 * BK;

  if (tiled_ok) {
    unsigned short* xb = (unsigned short*)d_ws;
    unsigned short* wb = xb + (size_t)x_n;
    int n8x = x_n / 8, n8w = w_n / 8;
    k_convert_x<<<(n8x + 255) / 256, 256, 0, stream>>>(x, xb, n8x);
    k_dequant_w<<<(n8w + 255) / 256, 256, 0, stream>>>(w, sc, wb, K, nblk, blk, n8w);
    hipFuncSetAttribute((const void*)k_gemm256,
                        hipFuncAttributeMaxDynamicSharedMemorySize, 131072);
    dim3 grid((T / BM) * (O / BN));
    k_gemm256<<<grid, 512, 131072, stream>>>(xb, wb, bias, out, T, O, K);
  } else {
    long long total = (long long)T * O;
    dim3 grid((unsigned)((total + 255) / 256));
    k_fallback<<<grid, 256, 0, stream>>>(x, w, sc, bias, out, T, O, K, nblk, blk);
  }
}